// Round 10
// baseline (229.703 us; speedup 1.0000x reference)
//
#include <hip/hip_runtime.h>

// B=4, C=64, H=64, W=64. Tokens N = C*H = 4096, feature dim D = W = 64.
// q = conv1x1(v1,wq,bq); k,v = conv1x1(v2,...); scores = q@k^T (no scale);
// softmax; out = attn@v. Output fp32, flat (B,C,H,W) == (B,N,D).
//
// R10: kill the P LDS roundtrip. PV switches to mfma_f32_16x16x16f16 with
// B = P^T taken DIRECTLY from QK's C-layout (k = g*4+j matches accS regs):
// O^T[d][q] = sum_fm mfma(A=V^T[nf][fm-keys], B=pk(accS[fm]), C). No Pt ->
// LDS 32KB -> 4 blocks/CU = 8 waves/SIMD (launch_bounds(512,8)); rescale &
// 1/l are lane-local (q=c) -> zero shuffles; float4/f16x4 output stores.
// S=16 -> grid 1024 = exactly 4 blocks/CU, one round.

#define Bn 4
#define Cc 64
#define HW 4096
#define Nn 4096
#define Dd 64
#define TS (Bn * Nn * Dd)   // elems per (B,N,D) tensor = 1048576
#define LOG2E 1.44269504088896340736f

typedef _Float16 f16;
typedef _Float16 f16x8 __attribute__((ext_vector_type(8)));
typedef _Float16 f16x4 __attribute__((ext_vector_type(4)));
typedef __fp16 fp16x2 __attribute__((ext_vector_type(2)));
typedef float f32x4 __attribute__((ext_vector_type(4)));

__device__ __forceinline__ int swz(int row, int col) {
    return row * 64 + (col ^ ((row & 7) << 3));
}

// Async global->LDS DMA, 16B per lane. LDS dest = uniform base + lane*16.
__device__ __forceinline__ void gl_lds16(const f16* g, f16* l) {
    __builtin_amdgcn_global_load_lds(
        (const __attribute__((address_space(1))) unsigned int*)g,
        (__attribute__((address_space(3))) unsigned int*)l, 16, 0, 0);
}

// ---------------------------------------------------------------------------
// Kernel 1: 1x1 conv. blockIdx.z 0..5: tensor = z>>1, channel-half = z&1.
// Q is single f16, pre-scaled by log2(e). SGPR (wave-uniform) weight reads.
__global__ __launch_bounds__(256) void qkv_conv(
    const float* __restrict__ v1, const float* __restrict__ v2,
    const float* __restrict__ wq, const float* __restrict__ bq,
    const float* __restrict__ wk, const float* __restrict__ bk,
    const float* __restrict__ wv, const float* __restrict__ bv,
    f16* __restrict__ Qh, f16* __restrict__ Kh, f16* __restrict__ Vh)
{
    const int t    = threadIdx.x;
    const int lane = t & 63;
    const int og   = __builtin_amdgcn_readfirstlane(t >> 6);  // 0..3 uniform
    const int b    = blockIdx.y;
    const int p    = blockIdx.x * 64 + lane;
    const int z    = blockIdx.z;        // 0..5
    const int zt   = z >> 1;            // 0=Q, 1=K, 2=V
    const int ch0  = (z & 1) * 32 + og * 8;

    const float* w    = (zt == 0) ? wq : (zt == 1) ? wk : wv;
    const float* bias = (zt == 0) ? bq : (zt == 1) ? bk : bv;
    const float* x    = ((zt == 0) ? v1 : v2) + (size_t)b * (Cc * HW) + p;

    float acc[8];
    #pragma unroll
    for (int j = 0; j < 8; ++j) acc[j] = bias[ch0 + j];
    #pragma unroll 16
    for (int c = 0; c < 64; ++c) {
        float xc = x[c * HW];
        #pragma unroll
        for (int j = 0; j < 8; ++j)
            acc[j] = fmaf(w[(ch0 + j) * 64 + c], xc, acc[j]);
    }

    f16* dst = (zt == 0) ? Qh : (zt == 1) ? Kh : Vh;
    const float scale = (zt == 0) ? LOG2E : 1.0f;
    #pragma unroll
    for (int j = 0; j < 8; ++j) {
        size_t idx = (size_t)b * (Nn * Dd) + (size_t)(ch0 + j) * 4096 + p;
        dst[idx] = (f16)(acc[j] * scale);
    }
}

// ---------------------------------------------------------------------------
// Kernel 2: transpose V (B,N,D) -> Vt (B,D,N).
__global__ __launch_bounds__(256) void vtrans(const f16* __restrict__ Vh,
                                              f16* __restrict__ Vt)
{
    __shared__ f16 tile[64][72];
    const int t  = threadIdx.x;
    const int n0 = blockIdx.x * 64;
    const int b  = blockIdx.y;
    for (int i = t; i < 4096; i += 256) {
        int r = i >> 6, c = i & 63;
        tile[r][c] = Vh[(size_t)b * (Nn * Dd) + (size_t)(n0 + r) * 64 + c];
    }
    __syncthreads();
    for (int i = t; i < 4096; i += 256) {
        int w = i >> 6, n = i & 63;
        Vt[(size_t)b * (Dd * Nn) + (size_t)w * Nn + n0 + n] = tile[n][w];
    }
}

// ---------------------------------------------------------------------------
// Kernel 3: flash attention, split-K. 512 threads = 8 waves x 32 q-rows.
// grid (16 q-blocks of 256 rows, S splits, 4 batches); S=16 -> 1024 blocks
// = exactly 4 resident blocks/CU (32KB LDS, 64 VGPR). gload_lds dbuf K/V,
// 1 barrier/tile.
// QK^T: S^T = mfma_16x16x32(A=K, B=Q^T): lane (g=lane>>4, c=lane&15) holds
//   S[key=fm*16+g*4+r][q=c] in accS[qf][fm][r]. Scores in log2 units.
// PV:  O^T = mfma_16x16x16(A=V^T-frag, B=pk_f16(accS)): lane holds
//   O[q=c][d=nf*16+g*4+r] -> softmax state, rescale, 1/l all lane-local.
__global__ __launch_bounds__(512, 8) void attn(
    const f16* __restrict__ Qhg, const f16* __restrict__ Khg,
    const f16* __restrict__ Vtg,
    float* __restrict__ out, f16* __restrict__ Opart, float2* __restrict__ ml)
{
    __shared__ __align__(16) f16 KT[2][4096];   // [key 64][d 64] swz, dbuf
    __shared__ __align__(16) f16 VT[2][4096];   // [d 64][key 64] swz, dbuf

    const int t    = threadIdx.x;
    const int lane = t & 63, wvi = t >> 6;      // 8 waves
    const int g = lane >> 4, c = lane & 15;
    const int b  = blockIdx.z;
    const int sp = blockIdx.y;
    const int S  = gridDim.y;
    const int n0 = blockIdx.x * 256;
    const int keysPerSplit = Nn / S;
    const int nTiles = keysPerSplit / 64;
    const int kbase = sp * keysPerSplit;

    // Staging: 512 threads cover all 64 rows x 64 cols in one shot.
    const int srow = t >> 3;                      // 0..63
    const int gc   = ((t & 7) ^ (srow & 7)) * 8;  // pre-swizzled global col
    f16* ldsKdst0 = &KT[0][(wvi * 8) * 64];       // wave-uniform dests
    f16* ldsKdst1 = &KT[1][(wvi * 8) * 64];
    f16* ldsVdst0 = &VT[0][(wvi * 8) * 64];
    f16* ldsVdst1 = &VT[1][(wvi * 8) * 64];

    const f16* Kb = Khg + (size_t)b * (Nn * Dd);
    const f16* Vb = Vtg + (size_t)b * (Dd * Nn);

    // Hoist Q B-fragments (single f16, pre-scaled by log2e).
    f16x8 qbh[2][2];
    #pragma unroll
    for (int qf = 0; qf < 2; ++qf) {
        const int qrow = n0 + wvi * 32 + qf * 16 + c;
        const f16* qhp = Qhg + ((size_t)b * Nn + qrow) * 64;
        #pragma unroll
        for (int ks = 0; ks < 2; ++ks)
            qbh[qf][ks] = *(const f16x8*)(qhp + ks * 32 + g * 8);
    }

    float m_run[2] = {-1e30f, -1e30f}, lpart[2] = {0.f, 0.f};
    f32x4 of[2][4];   // of[qf][nf][r] = O[q = c]["d" = nf*16+g*4+r]
    #pragma unroll
    for (int qf = 0; qf < 2; ++qf)
        #pragma unroll
        for (int nf = 0; nf < 4; ++nf)
            #pragma unroll
            for (int r = 0; r < 4; ++r) of[qf][nf][r] = 0.f;

    // Prologue: DMA tile 0 into buffer 0.
    gl_lds16(Kb + (size_t)(kbase + srow) * 64 + gc, ldsKdst0);
    gl_lds16(Vb + (size_t)srow * Nn + kbase + gc, ldsVdst0);
    __syncthreads();
    int cur = 0;

    for (int kt = 0; kt < nTiles; ++kt) {
        // Issue next tile's DMA into the free buffer (lands under compute).
        if (kt + 1 < nTiles) {
            const int k0n = kbase + (kt + 1) * 64;
            f16* kd = cur ? ldsKdst0 : ldsKdst1;
            f16* vd = cur ? ldsVdst0 : ldsVdst1;
            gl_lds16(Kb + (size_t)(k0n + srow) * 64 + gc, kd);
            gl_lds16(Vb + (size_t)srow * Nn + k0n + gc, vd);
        }

        const f16* KTc = KT[cur];
        const f16* VTc = VT[cur];

        // ---- QK^T (16x16x32, single pass; scores in log2 units) ----
        f32x4 accS[2][4];
        #pragma unroll
        for (int qf = 0; qf < 2; ++qf)
            #pragma unroll
            for (int fm = 0; fm < 4; ++fm)
                #pragma unroll
                for (int r = 0; r < 4; ++r) accS[qf][fm][r] = 0.f;
        #pragma unroll
        for (int fm = 0; fm < 4; ++fm) {
            const int key = fm * 16 + c;
            f16x8 kh0 = *(const f16x8*)(KTc + swz(key, g * 8));
            f16x8 kh1 = *(const f16x8*)(KTc + swz(key, 32 + g * 8));
            #pragma unroll
            for (int qf = 0; qf < 2; ++qf) {
                accS[qf][fm] = __builtin_amdgcn_mfma_f32_16x16x32_f16(kh0, qbh[qf][0], accS[qf][fm], 0, 0, 0);
                accS[qf][fm] = __builtin_amdgcn_mfma_f32_16x16x32_f16(kh1, qbh[qf][1], accS[qf][fm], 0, 0, 0);
            }
        }

        // ---- softmax (defer-max THR=8, log2 units) + pack P^T B-frags ----
        f16x4 pb[2][4];   // pb[qf][fm] = B[k=g*4+j][col=c] for 16x16x16 PV
        #pragma unroll
        for (int qf = 0; qf < 2; ++qf) {
            float m0 = fmaxf(fmaxf(accS[qf][0][0], accS[qf][0][1]),
                             fmaxf(accS[qf][0][2], accS[qf][0][3]));
            float m1 = fmaxf(fmaxf(accS[qf][1][0], accS[qf][1][1]),
                             fmaxf(accS[qf][1][2], accS[qf][1][3]));
            float m2 = fmaxf(fmaxf(accS[qf][2][0], accS[qf][2][1]),
                             fmaxf(accS[qf][2][2], accS[qf][2][3]));
            float m3 = fmaxf(fmaxf(accS[qf][3][0], accS[qf][3][1]),
                             fmaxf(accS[qf][3][2], accS[qf][3][3]));
            float tmax = fmaxf(fmaxf(m0, m1), fmaxf(m2, m3));
            tmax = fmaxf(tmax, __shfl_xor(tmax, 16));
            tmax = fmaxf(tmax, __shfl_xor(tmax, 32));
            if (!__all(tmax <= m_run[qf] + 8.f)) {
                const float mnew = fmaxf(m_run[qf], tmax);
                const float corr = exp2f(m_run[qf] - mnew);
                lpart[qf] *= corr;
                #pragma unroll
                for (int nf = 0; nf < 4; ++nf)
                    #pragma unroll
                    for (int r = 0; r < 4; ++r) of[qf][nf][r] *= corr;  // lane-local!
                m_run[qf] = mnew;
            }
            float s01 = 0.f, s23 = 0.f;
            #pragma unroll
            for (int fm = 0; fm < 4; ++fm) {
                #pragma unroll
                for (int r = 0; r < 4; ++r) {
                    float pp = exp2f(accS[qf][fm][r] - m_run[qf]);  // <= 2^8
                    accS[qf][fm][r] = pp;
                    if (fm < 2) s01 += pp; else s23 += pp;
                }
                union { f16x4 v4; fp16x2 h2[2]; } u;
                u.h2[0] = __builtin_amdgcn_cvt_pkrtz(accS[qf][fm][0], accS[qf][fm][1]);
                u.h2[1] = __builtin_amdgcn_cvt_pkrtz(accS[qf][fm][2], accS[qf][fm][3]);
                pb[qf][fm] = u.v4;
            }
            lpart[qf] += s01 + s23;   // per-lane; reduce at epilogue
        }

        // ---- PV (16x16x16): O^T += V^T-frag x P^T, no LDS roundtrip ----
        #pragma unroll
        for (int nf = 0; nf < 4; ++nf) {
            #pragma unroll
            for (int fm = 0; fm < 4; ++fm) {
                // A-frag: lane (g,c) holds V^T[nf*16 + c][fm*16 + g*4 + j]
                f16x4 va = *(const f16x4*)(VTc + swz(nf * 16 + c, fm * 16 + g * 4));
                of[0][nf] = __builtin_amdgcn_mfma_f32_16x16x16f16(va, pb[0][fm], of[0][nf], 0, 0, 0);
                of[1][nf] = __builtin_amdgcn_mfma_f32_16x16x16f16(va, pb[1][fm], of[1][nf], 0, 0, 0);
            }
        }

        // Barrier: compiler drains vmcnt (DMA done) + lgkmcnt before it.
        __syncthreads();
        cur ^= 1;
    }

    if (S == 1) {
        #pragma unroll
        for (int qf = 0; qf < 2; ++qf) {
            float lr = lpart[qf];
            lr += __shfl_xor(lr, 16);
            lr += __shfl_xor(lr, 32);
            const float linv = 1.0f / lr;   // lane-local (q = c)
            const int n = n0 + wvi * 32 + qf * 16 + c;
            #pragma unroll
            for (int nf = 0; nf < 4; ++nf) {
                float4 o4 = make_float4(of[qf][nf][0] * linv, of[qf][nf][1] * linv,
                                        of[qf][nf][2] * linv, of[qf][nf][3] * linv);
                *(float4*)(out + (((size_t)b * Nn + n) << 6) + nf * 16 + g * 4) = o4;
            }
        }
    } else {
        // Normalized f16 partials (O/l) + (m,l) per row for combine.
        #pragma unroll
        for (int qf = 0; qf < 2; ++qf) {
            float lr = lpart[qf];
            lr += __shfl_xor(lr, 16);
            lr += __shfl_xor(lr, 32);
            const float linv = 1.0f / lr;
            const int n = n0 + wvi * 32 + qf * 16 + c;
            size_t robase = (((size_t)sp * Bn + b) * Nn + n) << 6;
            #pragma unroll
            for (int nf = 0; nf < 4; ++nf) {
                union { f16x4 v4; fp16x2 h2[2]; } u;
                u.h2[0] = __builtin_amdgcn_cvt_pkrtz(of[qf][nf][0] * linv, of[qf][nf][1] * linv);
                u.h2[1] = __builtin_amdgcn_cvt_pkrtz(of[qf][nf][2] * linv, of[qf][nf][3] * linv);
                *(f16x4*)(Opart + robase + nf * 16 + g * 4) = u.v4;
            }
            if (g == 0) {
                ml[((size_t)sp * Bn + b) * Nn + n] = make_float2(m_run[qf], lr);
            }
        }
    }
}

// ---------------------------------------------------------------------------
// Kernel 4: combine normalized split partials. 8 outputs per thread.
// weight_s = exp2(m_s - M) * l_s; out = sum w_s O_s / sum w_s.
__global__ __launch_bounds__(256) void combine(
    const f16* __restrict__ Opart, const float2* __restrict__ ml,
    float* __restrict__ out, int S)
{
    const int idx8 = blockIdx.x * 256 + threadIdx.x;  // b*(N*8) + n*8 + w8
    const int w8 = idx8 & 7;
    const int n  = (idx8 >> 3) & (Nn - 1);
    const int b  = idx8 >> 15;
    float M = -1e30f;
    for (int s = 0; s < S; ++s)
        M = fmaxf(M, ml[((size_t)s * Bn + b) * Nn + n].x);
    float num[8];
    #pragma unroll
    for (int j = 0; j < 8; ++j) num[j] = 0.f;
    float den = 0.f;
    for (int s = 0; s < S; ++s) {
        float2 m2 = ml[((size_t)s * Bn + b) * Nn + n];
        float a = exp2f(m2.x - M) * m2.y;
        f16x8 o8 = *(const f16x8*)(Opart + ((((size_t)s * Bn + b) * Nn + n) << 6) + w8 * 8);
        #pragma unroll
        for (int j = 0; j < 8; ++j) num[j] += a * (float)o8[j];
        den += a;
    }
    const float di = 1.0f / den;
    float* op = out + (((size_t)b * Nn + n) << 6) + w8 * 8;
    float4 lo = make_float4(num[0] * di, num[1] * di, num[2] * di, num[3] * di);
    float4 hi = make_float4(num[4] * di, num[5] * di, num[6] * di, num[7] * di);
    *(float4*)op = lo;
    *(float4*)(op + 4) = hi;
}

// ---------------------------------------------------------------------------
extern "C" void kernel_launch(void* const* d_in, const int* in_sizes, int n_in,
                              void* d_out, int out_size, void* d_ws, size_t ws_size,
                              hipStream_t stream)
{
    const float* v1 = (const float*)d_in[0];
    const float* v2 = (const float*)d_in[1];
    const float* wq = (const float*)d_in[2];
    const float* bq = (const float*)d_in[3];
    const float* wk = (const float*)d_in[4];
    const float* bk = (const float*)d_in[5];
    const float* wv = (const float*)d_in[6];
    const float* bv = (const float*)d_in[7];
    float* out = (float*)d_out;

    char* ws = (char*)d_ws;
    const size_t T = (size_t)TS * sizeof(f16);  // 2 MB per f16 tensor
    f16* Qh = (f16*)(ws + 0 * T);
    f16* Kh = (f16*)(ws + 1 * T);
    f16* Vh = (f16*)(ws + 2 * T);
    f16* Vt = (f16*)(ws + 3 * T);
    const size_t base = 4 * T;                       // 8 MB
    const size_t opartBytes = (size_t)TS * 2;        // 2 MB per split (f16)
    const size_t mlBytes    = (size_t)Bn * Nn * 8;   // 128 KB per split

    int S = 1;
    if      (ws_size >= base + 16 * (opartBytes + mlBytes)) S = 16;
    else if (ws_size >= base +  8 * (opartBytes + mlBytes)) S = 8;
    else if (ws_size >= base +  4 * (opartBytes + mlBytes)) S = 4;
    else if (ws_size >= base +  2 * (opartBytes + mlBytes)) S = 2;

    f16*    Opart = (f16*)(ws + base);
    float2* mlp   = (float2*)(ws + base + (size_t)S * opartBytes);

    qkv_conv<<<dim3(64, 4, 6), 256, 0, stream>>>(v1, v2, wq, bq, wk, bk, wv, bv,
                                                 Qh, Kh, Vh);
    vtrans<<<dim3(64, 4), 256, 0, stream>>>(Vh, Vt);
    attn<<<dim3(16, S, 4), 512, 0, stream>>>(Qh, Kh, Vt, out, Opart, mlp);
    if (S > 1) {
        combine<<<(Bn * Nn * Dd / 8) / 256, 256, 0, stream>>>(Opart, mlp, out, S);
    }
}

// Round 11
// 84.896 us; speedup vs baseline: 2.7057x; 2.7057x over previous
//
#include <hip/hip_runtime.h>

// B=4, C=64, H=64, W=64. Tokens N = C*H = 4096, feature dim D = W = 64.
// q = conv1x1(v1,wq,bq); k,v = conv1x1(v2,...); scores = q@k^T (no scale);
// softmax; out = attn@v. Output fp32, flat (B,C,H,W) == (B,N,D).
//
// R11: R10's no-Pt PV (16x16x16 with P^T direct from QK C-layout) was correct
// but launch_bounds(512,8) + ~100 live VGPRs = spill storm (VGPR=32, 1GB
// scratch traffic). Fix: halve per-thread state -> 16 q-rows/wave (1 Q-frag).
// Peak live ~55 regs, fits the 64-VGPR budget of 8 waves/SIMD. Block = 8
// waves = 128 q-rows; grid (32, 8, 4) = 1024 = 4 blocks/CU, one round, 100%
// occupancy ceiling. LDS 32KB (K/V dbuf only).

#define Bn 4
#define Cc 64
#define HW 4096
#define Nn 4096
#define Dd 64
#define TS (Bn * Nn * Dd)   // elems per (B,N,D) tensor = 1048576
#define LOG2E 1.44269504088896340736f

typedef _Float16 f16;
typedef _Float16 f16x8 __attribute__((ext_vector_type(8)));
typedef _Float16 f16x4 __attribute__((ext_vector_type(4)));
typedef __fp16 fp16x2 __attribute__((ext_vector_type(2)));
typedef float f32x4 __attribute__((ext_vector_type(4)));

__device__ __forceinline__ int swz(int row, int col) {
    return row * 64 + (col ^ ((row & 7) << 3));
}

// Async global->LDS DMA, 16B per lane. LDS dest = uniform base + lane*16.
__device__ __forceinline__ void gl_lds16(const f16* g, f16* l) {
    __builtin_amdgcn_global_load_lds(
        (const __attribute__((address_space(1))) unsigned int*)g,
        (__attribute__((address_space(3))) unsigned int*)l, 16, 0, 0);
}

// ---------------------------------------------------------------------------
// Kernel 1: 1x1 conv. blockIdx.z 0..5: tensor = z>>1, channel-half = z&1.
// Q is single f16, pre-scaled by log2(e). SGPR (wave-uniform) weight reads.
__global__ __launch_bounds__(256) void qkv_conv(
    const float* __restrict__ v1, const float* __restrict__ v2,
    const float* __restrict__ wq, const float* __restrict__ bq,
    const float* __restrict__ wk, const float* __restrict__ bk,
    const float* __restrict__ wv, const float* __restrict__ bv,
    f16* __restrict__ Qh, f16* __restrict__ Kh, f16* __restrict__ Vh)
{
    const int t    = threadIdx.x;
    const int lane = t & 63;
    const int og   = __builtin_amdgcn_readfirstlane(t >> 6);  // 0..3 uniform
    const int b    = blockIdx.y;
    const int p    = blockIdx.x * 64 + lane;
    const int z    = blockIdx.z;        // 0..5
    const int zt   = z >> 1;            // 0=Q, 1=K, 2=V
    const int ch0  = (z & 1) * 32 + og * 8;

    const float* w    = (zt == 0) ? wq : (zt == 1) ? wk : wv;
    const float* bias = (zt == 0) ? bq : (zt == 1) ? bk : bv;
    const float* x    = ((zt == 0) ? v1 : v2) + (size_t)b * (Cc * HW) + p;

    float acc[8];
    #pragma unroll
    for (int j = 0; j < 8; ++j) acc[j] = bias[ch0 + j];
    #pragma unroll 16
    for (int c = 0; c < 64; ++c) {
        float xc = x[c * HW];
        #pragma unroll
        for (int j = 0; j < 8; ++j)
            acc[j] = fmaf(w[(ch0 + j) * 64 + c], xc, acc[j]);
    }

    f16* dst = (zt == 0) ? Qh : (zt == 1) ? Kh : Vh;
    const float scale = (zt == 0) ? LOG2E : 1.0f;
    #pragma unroll
    for (int j = 0; j < 8; ++j) {
        size_t idx = (size_t)b * (Nn * Dd) + (size_t)(ch0 + j) * 4096 + p;
        dst[idx] = (f16)(acc[j] * scale);
    }
}

// ---------------------------------------------------------------------------
// Kernel 2: transpose V (B,N,D) -> Vt (B,D,N).
__global__ __launch_bounds__(256) void vtrans(const f16* __restrict__ Vh,
                                              f16* __restrict__ Vt)
{
    __shared__ f16 tile[64][72];
    const int t  = threadIdx.x;
    const int n0 = blockIdx.x * 64;
    const int b  = blockIdx.y;
    for (int i = t; i < 4096; i += 256) {
        int r = i >> 6, c = i & 63;
        tile[r][c] = Vh[(size_t)b * (Nn * Dd) + (size_t)(n0 + r) * 64 + c];
    }
    __syncthreads();
    for (int i = t; i < 4096; i += 256) {
        int w = i >> 6, n = i & 63;
        Vt[(size_t)b * (Dd * Nn) + (size_t)w * Nn + n0 + n] = tile[n][w];
    }
}

// ---------------------------------------------------------------------------
// Kernel 3: flash attention, split-K. 512 threads = 8 waves x 16 q-rows.
// grid (32 q-blocks of 128 rows, S splits, 4 batches); S=8 -> 1024 blocks
// = exactly 4 resident blocks/CU (32KB LDS, <=64 VGPR), one round.
// QK^T: S^T = mfma_16x16x32(A=K, B=Q^T): lane (g=lane>>4, c=lane&15) holds
//   S[key=fm*16+g*4+r][q=c] in accS[fm][r]. Scores in log2 units.
// PV:  O^T = mfma_16x16x16(A=V^T-frag, B=pk_f16(accS)): lane holds
//   O[q=c][d=nf*16+g*4+r] -> softmax state, rescale, 1/l all lane-local.
__global__ __launch_bounds__(512, 8) void attn(
    const f16* __restrict__ Qhg, const f16* __restrict__ Khg,
    const f16* __restrict__ Vtg,
    float* __restrict__ out, f16* __restrict__ Opart, float2* __restrict__ ml)
{
    __shared__ __align__(16) f16 KT[2][4096];   // [key 64][d 64] swz, dbuf
    __shared__ __align__(16) f16 VT[2][4096];   // [d 64][key 64] swz, dbuf

    const int t    = threadIdx.x;
    const int lane = t & 63, wvi = t >> 6;      // 8 waves
    const int g = lane >> 4, c = lane & 15;
    const int b  = blockIdx.z;
    const int sp = blockIdx.y;
    const int S  = gridDim.y;
    const int n0 = blockIdx.x * 128;
    const int keysPerSplit = Nn / S;
    const int nTiles = keysPerSplit / 64;
    const int kbase = sp * keysPerSplit;

    // Staging: 512 threads cover all 64 rows x 64 cols in one shot.
    const int srow = t >> 3;                      // 0..63
    const int gc   = ((t & 7) ^ (srow & 7)) * 8;  // pre-swizzled global col
    f16* ldsKdst0 = &KT[0][(wvi * 8) * 64];       // wave-uniform dests
    f16* ldsKdst1 = &KT[1][(wvi * 8) * 64];
    f16* ldsVdst0 = &VT[0][(wvi * 8) * 64];
    f16* ldsVdst1 = &VT[1][(wvi * 8) * 64];

    const f16* Kb = Khg + (size_t)b * (Nn * Dd);
    const f16* Vb = Vtg + (size_t)b * (Dd * Nn);

    // Hoist Q B-fragment (single f16, pre-scaled by log2e). 16 rows: q = c.
    f16x8 qbh[2];
    {
        const int qrow = n0 + wvi * 16 + c;
        const f16* qhp = Qhg + ((size_t)b * Nn + qrow) * 64;
        #pragma unroll
        for (int ks = 0; ks < 2; ++ks)
            qbh[ks] = *(const f16x8*)(qhp + ks * 32 + g * 8);
    }

    float m_run = -1e30f, lpart = 0.f;
    f32x4 of[4];   // of[nf][r] = O[q = c][d = nf*16 + g*4 + r]
    #pragma unroll
    for (int nf = 0; nf < 4; ++nf)
        #pragma unroll
        for (int r = 0; r < 4; ++r) of[nf][r] = 0.f;

    // Prologue: DMA tile 0 into buffer 0.
    gl_lds16(Kb + (size_t)(kbase + srow) * 64 + gc, ldsKdst0);
    gl_lds16(Vb + (size_t)srow * Nn + kbase + gc, ldsVdst0);
    __syncthreads();
    int cur = 0;

    for (int kt = 0; kt < nTiles; ++kt) {
        // Issue next tile's DMA into the free buffer (lands under compute).
        if (kt + 1 < nTiles) {
            const int k0n = kbase + (kt + 1) * 64;
            f16* kd = cur ? ldsKdst0 : ldsKdst1;
            f16* vd = cur ? ldsVdst0 : ldsVdst1;
            gl_lds16(Kb + (size_t)(k0n + srow) * 64 + gc, kd);
            gl_lds16(Vb + (size_t)srow * Nn + k0n + gc, vd);
        }

        const f16* KTc = KT[cur];
        const f16* VTc = VT[cur];

        // ---- QK^T (16x16x32, single pass; scores in log2 units) ----
        f32x4 accS[4];
        #pragma unroll
        for (int fm = 0; fm < 4; ++fm)
            #pragma unroll
            for (int r = 0; r < 4; ++r) accS[fm][r] = 0.f;
        #pragma unroll
        for (int fm = 0; fm < 4; ++fm) {
            const int key = fm * 16 + c;
            f16x8 kh0 = *(const f16x8*)(KTc + swz(key, g * 8));
            f16x8 kh1 = *(const f16x8*)(KTc + swz(key, 32 + g * 8));
            accS[fm] = __builtin_amdgcn_mfma_f32_16x16x32_f16(kh0, qbh[0], accS[fm], 0, 0, 0);
            accS[fm] = __builtin_amdgcn_mfma_f32_16x16x32_f16(kh1, qbh[1], accS[fm], 0, 0, 0);
        }

        // ---- softmax (defer-max THR=8, log2 units) + pack P^T B-frags ----
        f16x4 pb[4];   // pb[fm] = B[k=g*4+j][col=c] for 16x16x16 PV
        {
            float m0 = fmaxf(fmaxf(accS[0][0], accS[0][1]),
                             fmaxf(accS[0][2], accS[0][3]));
            float m1 = fmaxf(fmaxf(accS[1][0], accS[1][1]),
                             fmaxf(accS[1][2], accS[1][3]));
            float m2 = fmaxf(fmaxf(accS[2][0], accS[2][1]),
                             fmaxf(accS[2][2], accS[2][3]));
            float m3 = fmaxf(fmaxf(accS[3][0], accS[3][1]),
                             fmaxf(accS[3][2], accS[3][3]));
            float tmax = fmaxf(fmaxf(m0, m1), fmaxf(m2, m3));
            tmax = fmaxf(tmax, __shfl_xor(tmax, 16));
            tmax = fmaxf(tmax, __shfl_xor(tmax, 32));
            if (!__all(tmax <= m_run + 8.f)) {
                const float mnew = fmaxf(m_run, tmax);
                const float corr = exp2f(m_run - mnew);
                lpart *= corr;
                #pragma unroll
                for (int nf = 0; nf < 4; ++nf)
                    #pragma unroll
                    for (int r = 0; r < 4; ++r) of[nf][r] *= corr;  // lane-local
                m_run = mnew;
            }
            float s01 = 0.f, s23 = 0.f;
            #pragma unroll
            for (int fm = 0; fm < 4; ++fm) {
                #pragma unroll
                for (int r = 0; r < 4; ++r) {
                    float pp = exp2f(accS[fm][r] - m_run);  // <= 2^8
                    accS[fm][r] = pp;
                    if (fm < 2) s01 += pp; else s23 += pp;
                }
                union { f16x4 v4; fp16x2 h2[2]; } u;
                u.h2[0] = __builtin_amdgcn_cvt_pkrtz(accS[fm][0], accS[fm][1]);
                u.h2[1] = __builtin_amdgcn_cvt_pkrtz(accS[fm][2], accS[fm][3]);
                pb[fm] = u.v4;
            }
            lpart += s01 + s23;   // per-lane; reduce at epilogue
        }

        // ---- PV (16x16x16): O^T += V^T-frag x P^T, no LDS roundtrip ----
        #pragma unroll
        for (int nf = 0; nf < 4; ++nf) {
            #pragma unroll
            for (int fm = 0; fm < 4; ++fm) {
                // A-frag: lane (g,c) holds V^T[nf*16 + c][fm*16 + g*4 + j]
                f16x4 va = *(const f16x4*)(VTc + swz(nf * 16 + c, fm * 16 + g * 4));
                of[nf] = __builtin_amdgcn_mfma_f32_16x16x16f16(va, pb[fm], of[nf], 0, 0, 0);
            }
        }

        // Barrier: compiler drains vmcnt (DMA done) + lgkmcnt before it.
        __syncthreads();
        cur ^= 1;
    }

    if (S == 1) {
        float lr = lpart;
        lr += __shfl_xor(lr, 16);
        lr += __shfl_xor(lr, 32);
        const float linv = 1.0f / lr;   // lane-local (q = c)
        const int n = n0 + wvi * 16 + c;
        #pragma unroll
        for (int nf = 0; nf < 4; ++nf) {
            float4 o4 = make_float4(of[nf][0] * linv, of[nf][1] * linv,
                                    of[nf][2] * linv, of[nf][3] * linv);
            *(float4*)(out + (((size_t)b * Nn + n) << 6) + nf * 16 + g * 4) = o4;
        }
    } else {
        // Normalized f16 partials (O/l) + (m,l) per row for combine.
        float lr = lpart;
        lr += __shfl_xor(lr, 16);
        lr += __shfl_xor(lr, 32);
        const float linv = 1.0f / lr;
        const int n = n0 + wvi * 16 + c;
        size_t robase = (((size_t)sp * Bn + b) * Nn + n) << 6;
        #pragma unroll
        for (int nf = 0; nf < 4; ++nf) {
            union { f16x4 v4; fp16x2 h2[2]; } u;
            u.h2[0] = __builtin_amdgcn_cvt_pkrtz(of[nf][0] * linv, of[nf][1] * linv);
            u.h2[1] = __builtin_amdgcn_cvt_pkrtz(of[nf][2] * linv, of[nf][3] * linv);
            *(f16x4*)(Opart + robase + nf * 16 + g * 4) = u.v4;
        }
        if (g == 0) {
            ml[((size_t)sp * Bn + b) * Nn + n] = make_float2(m_run, lr);
        }
    }
}

// ---------------------------------------------------------------------------
// Kernel 4: combine normalized split partials. 8 outputs per thread.
// weight_s = exp2(m_s - M) * l_s; out = sum w_s O_s / sum w_s.
__global__ __launch_bounds__(256) void combine(
    const f16* __restrict__ Opart, const float2* __restrict__ ml,
    float* __restrict__ out, int S)
{
    const int idx8 = blockIdx.x * 256 + threadIdx.x;  // b*(N*8) + n*8 + w8
    const int w8 = idx8 & 7;
    const int n  = (idx8 >> 3) & (Nn - 1);
    const int b  = idx8 >> 15;
    float M = -1e30f;
    for (int s = 0; s < S; ++s)
        M = fmaxf(M, ml[((size_t)s * Bn + b) * Nn + n].x);
    float num[8];
    #pragma unroll
    for (int j = 0; j < 8; ++j) num[j] = 0.f;
    float den = 0.f;
    for (int s = 0; s < S; ++s) {
        float2 m2 = ml[((size_t)s * Bn + b) * Nn + n];
        float a = exp2f(m2.x - M) * m2.y;
        f16x8 o8 = *(const f16x8*)(Opart + ((((size_t)s * Bn + b) * Nn + n) << 6) + w8 * 8);
        #pragma unroll
        for (int j = 0; j < 8; ++j) num[j] += a * (float)o8[j];
        den += a;
    }
    const float di = 1.0f / den;
    float* op = out + (((size_t)b * Nn + n) << 6) + w8 * 8;
    float4 lo = make_float4(num[0] * di, num[1] * di, num[2] * di, num[3] * di);
    float4 hi = make_float4(num[4] * di, num[5] * di, num[6] * di, num[7] * di);
    *(float4*)op = lo;
    *(float4*)(op + 4) = hi;
}

// ---------------------------------------------------------------------------
extern "C" void kernel_launch(void* const* d_in, const int* in_sizes, int n_in,
                              void* d_out, int out_size, void* d_ws, size_t ws_size,
                              hipStream_t stream)
{
    const float* v1 = (const float*)d_in[0];
    const float* v2 = (const float*)d_in[1];
    const float* wq = (const float*)d_in[2];
    const float* bq = (const float*)d_in[3];
    const float* wk = (const float*)d_in[4];
    const float* bk = (const float*)d_in[5];
    const float* wv = (const float*)d_in[6];
    const float* bv = (const float*)d_in[7];
    float* out = (float*)d_out;

    char* ws = (char*)d_ws;
    const size_t T = (size_t)TS * sizeof(f16);  // 2 MB per f16 tensor
    f16* Qh = (f16*)(ws + 0 * T);
    f16* Kh = (f16*)(ws + 1 * T);
    f16* Vh = (f16*)(ws + 2 * T);
    f16* Vt = (f16*)(ws + 3 * T);
    const size_t base = 4 * T;                       // 8 MB
    const size_t opartBytes = (size_t)TS * 2;        // 2 MB per split (f16)
    const size_t mlBytes    = (size_t)Bn * Nn * 8;   // 128 KB per split

    int S = 1;
    if      (ws_size >= base + 8 * (opartBytes + mlBytes)) S = 8;
    else if (ws_size >= base + 4 * (opartBytes + mlBytes)) S = 4;
    else if (ws_size >= base + 2 * (opartBytes + mlBytes)) S = 2;

    f16*    Opart = (f16*)(ws + base);
    float2* mlp   = (float2*)(ws + base + (size_t)S * opartBytes);

    qkv_conv<<<dim3(64, 4, 6), 256, 0, stream>>>(v1, v2, wq, bq, wk, bk, wv, bv,
                                                 Qh, Kh, Vh);
    vtrans<<<dim3(64, 4), 256, 0, stream>>>(Vh, Vt);
    attn<<<dim3(32, S, 4), 512, 0, stream>>>(Qh, Kh, Vt, out, Opart, mlp);
    if (S > 1) {
        combine<<<(Bn * Nn * Dd / 8) / 256, 256, 0, stream>>>(Opart, mlp, out, S);
    }
}

// Round 12
// 72.989 us; speedup vs baseline: 3.1471x; 1.1631x over previous
//
#include <hip/hip_runtime.h>

// B=4, C=64, H=64, W=64. Tokens N = C*H = 4096, feature dim D = W = 64.
// q = conv1x1(v1,wq,bq); k,v = conv1x1(v2,...); scores = q@k^T (no scale);
// softmax; out = attn@v. Output fp32, flat (B,C,H,W) == (B,N,D).
//
// R12 = R11 with launch_bounds(512,6). R11's (512,8) = 64-reg UNIFIED budget
// (VGPR+AGPR share the file on gfx950) vs ~80 live -> 47MB scratch spill.
// (512,6) = 85-reg budget: spill-free at 75% occupancy ceiling (3 blk/CU).

#define Bn 4
#define Cc 64
#define HW 4096
#define Nn 4096
#define Dd 64
#define TS (Bn * Nn * Dd)   // elems per (B,N,D) tensor = 1048576
#define LOG2E 1.44269504088896340736f

typedef _Float16 f16;
typedef _Float16 f16x8 __attribute__((ext_vector_type(8)));
typedef _Float16 f16x4 __attribute__((ext_vector_type(4)));
typedef __fp16 fp16x2 __attribute__((ext_vector_type(2)));
typedef float f32x4 __attribute__((ext_vector_type(4)));

__device__ __forceinline__ int swz(int row, int col) {
    return row * 64 + (col ^ ((row & 7) << 3));
}

// Async global->LDS DMA, 16B per lane. LDS dest = uniform base + lane*16.
__device__ __forceinline__ void gl_lds16(const f16* g, f16* l) {
    __builtin_amdgcn_global_load_lds(
        (const __attribute__((address_space(1))) unsigned int*)g,
        (__attribute__((address_space(3))) unsigned int*)l, 16, 0, 0);
}

// ---------------------------------------------------------------------------
// Kernel 1: 1x1 conv. blockIdx.z 0..5: tensor = z>>1, channel-half = z&1.
// Q is single f16, pre-scaled by log2(e). SGPR (wave-uniform) weight reads.
__global__ __launch_bounds__(256) void qkv_conv(
    const float* __restrict__ v1, const float* __restrict__ v2,
    const float* __restrict__ wq, const float* __restrict__ bq,
    const float* __restrict__ wk, const float* __restrict__ bk,
    const float* __restrict__ wv, const float* __restrict__ bv,
    f16* __restrict__ Qh, f16* __restrict__ Kh, f16* __restrict__ Vh)
{
    const int t    = threadIdx.x;
    const int lane = t & 63;
    const int og   = __builtin_amdgcn_readfirstlane(t >> 6);  // 0..3 uniform
    const int b    = blockIdx.y;
    const int p    = blockIdx.x * 64 + lane;
    const int z    = blockIdx.z;        // 0..5
    const int zt   = z >> 1;            // 0=Q, 1=K, 2=V
    const int ch0  = (z & 1) * 32 + og * 8;

    const float* w    = (zt == 0) ? wq : (zt == 1) ? wk : wv;
    const float* bias = (zt == 0) ? bq : (zt == 1) ? bk : bv;
    const float* x    = ((zt == 0) ? v1 : v2) + (size_t)b * (Cc * HW) + p;

    float acc[8];
    #pragma unroll
    for (int j = 0; j < 8; ++j) acc[j] = bias[ch0 + j];
    #pragma unroll 16
    for (int c = 0; c < 64; ++c) {
        float xc = x[c * HW];
        #pragma unroll
        for (int j = 0; j < 8; ++j)
            acc[j] = fmaf(w[(ch0 + j) * 64 + c], xc, acc[j]);
    }

    f16* dst = (zt == 0) ? Qh : (zt == 1) ? Kh : Vh;
    const float scale = (zt == 0) ? LOG2E : 1.0f;
    #pragma unroll
    for (int j = 0; j < 8; ++j) {
        size_t idx = (size_t)b * (Nn * Dd) + (size_t)(ch0 + j) * 4096 + p;
        dst[idx] = (f16)(acc[j] * scale);
    }
}

// ---------------------------------------------------------------------------
// Kernel 2: transpose V (B,N,D) -> Vt (B,D,N).
__global__ __launch_bounds__(256) void vtrans(const f16* __restrict__ Vh,
                                              f16* __restrict__ Vt)
{
    __shared__ f16 tile[64][72];
    const int t  = threadIdx.x;
    const int n0 = blockIdx.x * 64;
    const int b  = blockIdx.y;
    for (int i = t; i < 4096; i += 256) {
        int r = i >> 6, c = i & 63;
        tile[r][c] = Vh[(size_t)b * (Nn * Dd) + (size_t)(n0 + r) * 64 + c];
    }
    __syncthreads();
    for (int i = t; i < 4096; i += 256) {
        int w = i >> 6, n = i & 63;
        Vt[(size_t)b * (Dd * Nn) + (size_t)w * Nn + n0 + n] = tile[n][w];
    }
}

// ---------------------------------------------------------------------------
// Kernel 3: flash attention, split-K. 512 threads = 8 waves x 16 q-rows.
// grid (32 q-blocks of 128 rows, S splits, 4 batches); S=8 -> 1024 blocks,
// 3 resident blocks/CU at (512,6). LDS 32KB (K/V dbuf only).
// QK^T: S^T = mfma_16x16x32(A=K, B=Q^T): lane (g=lane>>4, c=lane&15) holds
//   S[key=fm*16+g*4+r][q=c] in accS[fm][r]. Scores in log2 units.
// PV:  O^T = mfma_16x16x16(A=V^T-frag, B=pk_f16(accS)): lane holds
//   O[q=c][d=nf*16+g*4+r] -> softmax state, rescale, 1/l all lane-local.
__global__ __launch_bounds__(512, 6) void attn(
    const f16* __restrict__ Qhg, const f16* __restrict__ Khg,
    const f16* __restrict__ Vtg,
    float* __restrict__ out, f16* __restrict__ Opart, float2* __restrict__ ml)
{
    __shared__ __align__(16) f16 KT[2][4096];   // [key 64][d 64] swz, dbuf
    __shared__ __align__(16) f16 VT[2][4096];   // [d 64][key 64] swz, dbuf

    const int t    = threadIdx.x;
    const int lane = t & 63, wvi = t >> 6;      // 8 waves
    const int g = lane >> 4, c = lane & 15;
    const int b  = blockIdx.z;
    const int sp = blockIdx.y;
    const int S  = gridDim.y;
    const int n0 = blockIdx.x * 128;
    const int keysPerSplit = Nn / S;
    const int nTiles = keysPerSplit / 64;
    const int kbase = sp * keysPerSplit;

    // Staging: 512 threads cover all 64 rows x 64 cols in one shot.
    const int srow = t >> 3;                      // 0..63
    const int gc   = ((t & 7) ^ (srow & 7)) * 8;  // pre-swizzled global col
    f16* ldsKdst0 = &KT[0][(wvi * 8) * 64];       // wave-uniform dests
    f16* ldsKdst1 = &KT[1][(wvi * 8) * 64];
    f16* ldsVdst0 = &VT[0][(wvi * 8) * 64];
    f16* ldsVdst1 = &VT[1][(wvi * 8) * 64];

    const f16* Kb = Khg + (size_t)b * (Nn * Dd);
    const f16* Vb = Vtg + (size_t)b * (Dd * Nn);

    // Hoist Q B-fragment (single f16, pre-scaled by log2e). 16 rows: q = c.
    f16x8 qbh[2];
    {
        const int qrow = n0 + wvi * 16 + c;
        const f16* qhp = Qhg + ((size_t)b * Nn + qrow) * 64;
        #pragma unroll
        for (int ks = 0; ks < 2; ++ks)
            qbh[ks] = *(const f16x8*)(qhp + ks * 32 + g * 8);
    }

    float m_run = -1e30f, lpart = 0.f;
    f32x4 of[4];   // of[nf][r] = O[q = c][d = nf*16 + g*4 + r]
    #pragma unroll
    for (int nf = 0; nf < 4; ++nf)
        #pragma unroll
        for (int r = 0; r < 4; ++r) of[nf][r] = 0.f;

    // Prologue: DMA tile 0 into buffer 0.
    gl_lds16(Kb + (size_t)(kbase + srow) * 64 + gc, ldsKdst0);
    gl_lds16(Vb + (size_t)srow * Nn + kbase + gc, ldsVdst0);
    __syncthreads();
    int cur = 0;

    for (int kt = 0; kt < nTiles; ++kt) {
        // Issue next tile's DMA into the free buffer (lands under compute).
        if (kt + 1 < nTiles) {
            const int k0n = kbase + (kt + 1) * 64;
            f16* kd = cur ? ldsKdst0 : ldsKdst1;
            f16* vd = cur ? ldsVdst0 : ldsVdst1;
            gl_lds16(Kb + (size_t)(k0n + srow) * 64 + gc, kd);
            gl_lds16(Vb + (size_t)srow * Nn + k0n + gc, vd);
        }

        const f16* KTc = KT[cur];
        const f16* VTc = VT[cur];

        // ---- QK^T (16x16x32, single pass; scores in log2 units) ----
        f32x4 accS[4];
        #pragma unroll
        for (int fm = 0; fm < 4; ++fm)
            #pragma unroll
            for (int r = 0; r < 4; ++r) accS[fm][r] = 0.f;
        #pragma unroll
        for (int fm = 0; fm < 4; ++fm) {
            const int key = fm * 16 + c;
            f16x8 kh0 = *(const f16x8*)(KTc + swz(key, g * 8));
            f16x8 kh1 = *(const f16x8*)(KTc + swz(key, 32 + g * 8));
            accS[fm] = __builtin_amdgcn_mfma_f32_16x16x32_f16(kh0, qbh[0], accS[fm], 0, 0, 0);
            accS[fm] = __builtin_amdgcn_mfma_f32_16x16x32_f16(kh1, qbh[1], accS[fm], 0, 0, 0);
        }

        // ---- softmax (defer-max THR=8, log2 units) + pack P^T B-frags ----
        f16x4 pb[4];   // pb[fm] = B[k=g*4+j][col=c] for 16x16x16 PV
        {
            float m0 = fmaxf(fmaxf(accS[0][0], accS[0][1]),
                             fmaxf(accS[0][2], accS[0][3]));
            float m1 = fmaxf(fmaxf(accS[1][0], accS[1][1]),
                             fmaxf(accS[1][2], accS[1][3]));
            float m2 = fmaxf(fmaxf(accS[2][0], accS[2][1]),
                             fmaxf(accS[2][2], accS[2][3]));
            float m3 = fmaxf(fmaxf(accS[3][0], accS[3][1]),
                             fmaxf(accS[3][2], accS[3][3]));
            float tmax = fmaxf(fmaxf(m0, m1), fmaxf(m2, m3));
            tmax = fmaxf(tmax, __shfl_xor(tmax, 16));
            tmax = fmaxf(tmax, __shfl_xor(tmax, 32));
            if (!__all(tmax <= m_run + 8.f)) {
                const float mnew = fmaxf(m_run, tmax);
                const float corr = exp2f(m_run - mnew);
                lpart *= corr;
                #pragma unroll
                for (int nf = 0; nf < 4; ++nf)
                    #pragma unroll
                    for (int r = 0; r < 4; ++r) of[nf][r] *= corr;  // lane-local
                m_run = mnew;
            }
            float s01 = 0.f, s23 = 0.f;
            #pragma unroll
            for (int fm = 0; fm < 4; ++fm) {
                #pragma unroll
                for (int r = 0; r < 4; ++r) {
                    float pp = exp2f(accS[fm][r] - m_run);  // <= 2^8
                    accS[fm][r] = pp;
                    if (fm < 2) s01 += pp; else s23 += pp;
                }
                union { f16x4 v4; fp16x2 h2[2]; } u;
                u.h2[0] = __builtin_amdgcn_cvt_pkrtz(accS[fm][0], accS[fm][1]);
                u.h2[1] = __builtin_amdgcn_cvt_pkrtz(accS[fm][2], accS[fm][3]);
                pb[fm] = u.v4;
            }
            lpart += s01 + s23;   // per-lane; reduce at epilogue
        }

        // ---- PV (16x16x16): O^T += V^T-frag x P^T, no LDS roundtrip ----
        #pragma unroll
        for (int nf = 0; nf < 4; ++nf) {
            #pragma unroll
            for (int fm = 0; fm < 4; ++fm) {
                // A-frag: lane (g,c) holds V^T[nf*16 + c][fm*16 + g*4 + j]
                f16x4 va = *(const f16x4*)(VTc + swz(nf * 16 + c, fm * 16 + g * 4));
                of[nf] = __builtin_amdgcn_mfma_f32_16x16x16f16(va, pb[fm], of[nf], 0, 0, 0);
            }
        }

        // Barrier: compiler drains vmcnt (DMA done) + lgkmcnt before it.
        __syncthreads();
        cur ^= 1;
    }

    if (S == 1) {
        float lr = lpart;
        lr += __shfl_xor(lr, 16);
        lr += __shfl_xor(lr, 32);
        const float linv = 1.0f / lr;   // lane-local (q = c)
        const int n = n0 + wvi * 16 + c;
        #pragma unroll
        for (int nf = 0; nf < 4; ++nf) {
            float4 o4 = make_float4(of[nf][0] * linv, of[nf][1] * linv,
                                    of[nf][2] * linv, of[nf][3] * linv);
            *(float4*)(out + (((size_t)b * Nn + n) << 6) + nf * 16 + g * 4) = o4;
        }
    } else {
        // Normalized f16 partials (O/l) + (m,l) per row for combine.
        float lr = lpart;
        lr += __shfl_xor(lr, 16);
        lr += __shfl_xor(lr, 32);
        const float linv = 1.0f / lr;
        const int n = n0 + wvi * 16 + c;
        size_t robase = (((size_t)sp * Bn + b) * Nn + n) << 6;
        #pragma unroll
        for (int nf = 0; nf < 4; ++nf) {
            union { f16x4 v4; fp16x2 h2[2]; } u;
            u.h2[0] = __builtin_amdgcn_cvt_pkrtz(of[nf][0] * linv, of[nf][1] * linv);
            u.h2[1] = __builtin_amdgcn_cvt_pkrtz(of[nf][2] * linv, of[nf][3] * linv);
            *(f16x4*)(Opart + robase + nf * 16 + g * 4) = u.v4;
        }
        if (g == 0) {
            ml[((size_t)sp * Bn + b) * Nn + n] = make_float2(m_run, lr);
        }
    }
}

// ---------------------------------------------------------------------------
// Kernel 4: combine normalized split partials. 8 outputs per thread.
// weight_s = exp2(m_s - M) * l_s; out = sum w_s O_s / sum w_s.
__global__ __launch_bounds__(256) void combine(
    const f16* __restrict__ Opart, const float2* __restrict__ ml,
    float* __restrict__ out, int S)
{
    const int idx8 = blockIdx.x * 256 + threadIdx.x;  // b*(N*8) + n*8 + w8
    const int w8 = idx8 & 7;
    const int n  = (idx8 >> 3) & (Nn - 1);
    const int b  = idx8 >> 15;
    float M = -1e30f;
    for (int s = 0; s < S; ++s)
        M = fmaxf(M, ml[((size_t)s * Bn + b) * Nn + n].x);
    float num[8];
    #pragma unroll
    for (int j = 0; j < 8; ++j) num[j] = 0.f;
    float den = 0.f;
    for (int s = 0; s < S; ++s) {
        float2 m2 = ml[((size_t)s * Bn + b) * Nn + n];
        float a = exp2f(m2.x - M) * m2.y;
        f16x8 o8 = *(const f16x8*)(Opart + ((((size_t)s * Bn + b) * Nn + n) << 6) + w8 * 8);
        #pragma unroll
        for (int j = 0; j < 8; ++j) num[j] += a * (float)o8[j];
        den += a;
    }
    const float di = 1.0f / den;
    float* op = out + (((size_t)b * Nn + n) << 6) + w8 * 8;
    float4 lo = make_float4(num[0] * di, num[1] * di, num[2] * di, num[3] * di);
    float4 hi = make_float4(num[4] * di, num[5] * di, num[6] * di, num[7] * di);
    *(float4*)op = lo;
    *(float4*)(op + 4) = hi;
}

// ---------------------------------------------------------------------------
extern "C" void kernel_launch(void* const* d_in, const int* in_sizes, int n_in,
                              void* d_out, int out_size, void* d_ws, size_t ws_size,
                              hipStream_t stream)
{
    const float* v1 = (const float*)d_in[0];
    const float* v2 = (const float*)d_in[1];
    const float* wq = (const float*)d_in[2];
    const float* bq = (const float*)d_in[3];
    const float* wk = (const float*)d_in[4];
    const float* bk = (const float*)d_in[5];
    const float* wv = (const float*)d_in[6];
    const float* bv = (const float*)d_in[7];
    float* out = (float*)d_out;

    char* ws = (char*)d_ws;
    const size_t T = (size_t)TS * sizeof(f16);  // 2 MB per f16 tensor
    f16* Qh = (f16*)(ws + 0 * T);
    f16* Kh = (f16*)(ws + 1 * T);
    f16* Vh = (f16*)(ws + 2 * T);
    f16* Vt = (f16*)(ws + 3 * T);
    const size_t base = 4 * T;                       // 8 MB
    const size_t opartBytes = (size_t)TS * 2;        // 2 MB per split (f16)
    const size_t mlBytes    = (size_t)Bn * Nn * 8;   // 128 KB per split

    int S = 1;
    if      (ws_size >= base + 8 * (opartBytes + mlBytes)) S = 8;
    else if (ws_size >= base + 4 * (opartBytes + mlBytes)) S = 4;
    else if (ws_size >= base + 2 * (opartBytes + mlBytes)) S = 2;

    f16*    Opart = (f16*)(ws + base);
    float2* mlp   = (float2*)(ws + base + (size_t)S * opartBytes);

    qkv_conv<<<dim3(64, 4, 6), 256, 0, stream>>>(v1, v2, wq, bq, wk, bk, wv, bv,
                                                 Qh, Kh, Vh);
    vtrans<<<dim3(64, 4), 256, 0, stream>>>(Vh, Vt);
    attn<<<dim3(32, S, 4), 512, 0, stream>>>(Qh, Kh, Vt, out, Opart, mlp);
    if (S > 1) {
        combine<<<(Bn * Nn * Dd / 8) / 256, 256, 0, stream>>>(Opart, mlp, out, S);
    }
}

// Round 13
// 71.194 us; speedup vs baseline: 3.2265x; 1.0252x over previous
//
#include <hip/hip_runtime.h>

// B=4, C=64, H=64, W=64. Tokens N = C*H = 4096, feature dim D = W = 64.
// q = conv1x1(v1,wq,bq); k,v = conv1x1(v2,...); scores = q@k^T (no scale);
// softmax; out = attn@v. Output fp32, flat (B,C,H,W) == (B,N,D).
//
// R13: R12 was LDS-read-pipe bound (~208 DS cyc/wave-tile for 16 q-rows).
// Restore 32 q-rows/wave (qf=2) on the no-Pt structure: V A-frag reads are
// qf-independent -> same DS serves 2x rows. Budget: launch_bounds(512,4)
// (128 regs, ~110 live, no spill). Block 8 waves = 256 q-rows; grid
// (16,8,4) = 512 = exactly 2 blocks/CU = 16 waves/CU, one round.

#define Bn 4
#define Cc 64
#define HW 4096
#define Nn 4096
#define Dd 64
#define TS (Bn * Nn * Dd)   // elems per (B,N,D) tensor = 1048576
#define LOG2E 1.44269504088896340736f

typedef _Float16 f16;
typedef _Float16 f16x8 __attribute__((ext_vector_type(8)));
typedef _Float16 f16x4 __attribute__((ext_vector_type(4)));
typedef __fp16 fp16x2 __attribute__((ext_vector_type(2)));
typedef float f32x4 __attribute__((ext_vector_type(4)));

__device__ __forceinline__ int swz(int row, int col) {
    return row * 64 + (col ^ ((row & 7) << 3));
}

// Async global->LDS DMA, 16B per lane. LDS dest = uniform base + lane*16.
__device__ __forceinline__ void gl_lds16(const f16* g, f16* l) {
    __builtin_amdgcn_global_load_lds(
        (const __attribute__((address_space(1))) unsigned int*)g,
        (__attribute__((address_space(3))) unsigned int*)l, 16, 0, 0);
}

// ---------------------------------------------------------------------------
// Kernel 1: 1x1 conv. blockIdx.z 0..5: tensor = z>>1, channel-half = z&1.
// Q is single f16, pre-scaled by log2(e). SGPR (wave-uniform) weight reads.
__global__ __launch_bounds__(256) void qkv_conv(
    const float* __restrict__ v1, const float* __restrict__ v2,
    const float* __restrict__ wq, const float* __restrict__ bq,
    const float* __restrict__ wk, const float* __restrict__ bk,
    const float* __restrict__ wv, const float* __restrict__ bv,
    f16* __restrict__ Qh, f16* __restrict__ Kh, f16* __restrict__ Vh)
{
    const int t    = threadIdx.x;
    const int lane = t & 63;
    const int og   = __builtin_amdgcn_readfirstlane(t >> 6);  // 0..3 uniform
    const int b    = blockIdx.y;
    const int p    = blockIdx.x * 64 + lane;
    const int z    = blockIdx.z;        // 0..5
    const int zt   = z >> 1;            // 0=Q, 1=K, 2=V
    const int ch0  = (z & 1) * 32 + og * 8;

    const float* w    = (zt == 0) ? wq : (zt == 1) ? wk : wv;
    const float* bias = (zt == 0) ? bq : (zt == 1) ? bk : bv;
    const float* x    = ((zt == 0) ? v1 : v2) + (size_t)b * (Cc * HW) + p;

    float acc[8];
    #pragma unroll
    for (int j = 0; j < 8; ++j) acc[j] = bias[ch0 + j];
    #pragma unroll 16
    for (int c = 0; c < 64; ++c) {
        float xc = x[c * HW];
        #pragma unroll
        for (int j = 0; j < 8; ++j)
            acc[j] = fmaf(w[(ch0 + j) * 64 + c], xc, acc[j]);
    }

    f16* dst = (zt == 0) ? Qh : (zt == 1) ? Kh : Vh;
    const float scale = (zt == 0) ? LOG2E : 1.0f;
    #pragma unroll
    for (int j = 0; j < 8; ++j) {
        size_t idx = (size_t)b * (Nn * Dd) + (size_t)(ch0 + j) * 4096 + p;
        dst[idx] = (f16)(acc[j] * scale);
    }
}

// ---------------------------------------------------------------------------
// Kernel 2: transpose V (B,N,D) -> Vt (B,D,N).
__global__ __launch_bounds__(256) void vtrans(const f16* __restrict__ Vh,
                                              f16* __restrict__ Vt)
{
    __shared__ f16 tile[64][72];
    const int t  = threadIdx.x;
    const int n0 = blockIdx.x * 64;
    const int b  = blockIdx.y;
    for (int i = t; i < 4096; i += 256) {
        int r = i >> 6, c = i & 63;
        tile[r][c] = Vh[(size_t)b * (Nn * Dd) + (size_t)(n0 + r) * 64 + c];
    }
    __syncthreads();
    for (int i = t; i < 4096; i += 256) {
        int w = i >> 6, n = i & 63;
        Vt[(size_t)b * (Dd * Nn) + (size_t)w * Nn + n0 + n] = tile[n][w];
    }
}

// ---------------------------------------------------------------------------
// Kernel 3: flash attention, split-K. 512 threads = 8 waves x 32 q-rows.
// grid (16 q-blocks of 256 rows, S splits, 4 batches); S=8 -> 512 blocks
// = exactly 2 resident blocks/CU at (512,4). LDS 32KB (K/V dbuf, no Pt).
// QK^T: S^T = mfma_16x16x32(A=K, B=Q^T): lane (g=lane>>4, c=lane&15) holds
//   S[key=fm*16+g*4+r][q=c] in accS[qf][fm][r]. Scores in log2 units.
// PV:  O^T = mfma_16x16x16(A=V^T-frag, B=pk_f16(accS)): lane holds
//   O[q=c][d=nf*16+g*4+r]; V A-frag is qf-independent (read once, used 2x).
__global__ __launch_bounds__(512, 4) void attn(
    const f16* __restrict__ Qhg, const f16* __restrict__ Khg,
    const f16* __restrict__ Vtg,
    float* __restrict__ out, f16* __restrict__ Opart, float2* __restrict__ ml)
{
    __shared__ __align__(16) f16 KT[2][4096];   // [key 64][d 64] swz, dbuf
    __shared__ __align__(16) f16 VT[2][4096];   // [d 64][key 64] swz, dbuf

    const int t    = threadIdx.x;
    const int lane = t & 63, wvi = t >> 6;      // 8 waves
    const int g = lane >> 4, c = lane & 15;
    const int b  = blockIdx.z;
    const int sp = blockIdx.y;
    const int S  = gridDim.y;
    const int n0 = blockIdx.x * 256;
    const int keysPerSplit = Nn / S;
    const int nTiles = keysPerSplit / 64;
    const int kbase = sp * keysPerSplit;

    // Staging: 512 threads cover all 64 rows x 64 cols in one shot.
    const int srow = t >> 3;                      // 0..63
    const int gc   = ((t & 7) ^ (srow & 7)) * 8;  // pre-swizzled global col
    f16* ldsKdst0 = &KT[0][(wvi * 8) * 64];       // wave-uniform dests
    f16* ldsKdst1 = &KT[1][(wvi * 8) * 64];
    f16* ldsVdst0 = &VT[0][(wvi * 8) * 64];
    f16* ldsVdst1 = &VT[1][(wvi * 8) * 64];

    const f16* Kb = Khg + (size_t)b * (Nn * Dd);
    const f16* Vb = Vtg + (size_t)b * (Dd * Nn);

    // Hoist Q B-fragments (single f16, pre-scaled by log2e); q-rows:
    // qf*16 + c within the wave's 32-row strip.
    f16x8 qbh[2][2];
    #pragma unroll
    for (int qf = 0; qf < 2; ++qf) {
        const int qrow = n0 + wvi * 32 + qf * 16 + c;
        const f16* qhp = Qhg + ((size_t)b * Nn + qrow) * 64;
        #pragma unroll
        for (int ks = 0; ks < 2; ++ks)
            qbh[qf][ks] = *(const f16x8*)(qhp + ks * 32 + g * 8);
    }

    float m_run[2] = {-1e30f, -1e30f}, lpart[2] = {0.f, 0.f};
    f32x4 of[2][4];   // of[qf][nf][r] = O[q = c][d = nf*16 + g*4 + r]
    #pragma unroll
    for (int qf = 0; qf < 2; ++qf)
        #pragma unroll
        for (int nf = 0; nf < 4; ++nf)
            #pragma unroll
            for (int r = 0; r < 4; ++r) of[qf][nf][r] = 0.f;

    // Prologue: DMA tile 0 into buffer 0.
    gl_lds16(Kb + (size_t)(kbase + srow) * 64 + gc, ldsKdst0);
    gl_lds16(Vb + (size_t)srow * Nn + kbase + gc, ldsVdst0);
    __syncthreads();
    int cur = 0;

    for (int kt = 0; kt < nTiles; ++kt) {
        // Issue next tile's DMA into the free buffer (lands under compute).
        if (kt + 1 < nTiles) {
            const int k0n = kbase + (kt + 1) * 64;
            f16* kd = cur ? ldsKdst0 : ldsKdst1;
            f16* vd = cur ? ldsVdst0 : ldsVdst1;
            gl_lds16(Kb + (size_t)(k0n + srow) * 64 + gc, kd);
            gl_lds16(Vb + (size_t)srow * Nn + k0n + gc, vd);
        }

        const f16* KTc = KT[cur];
        const f16* VTc = VT[cur];

        // ---- QK^T (16x16x32; one K-read feeds both qf) ----
        f32x4 accS[2][4];
        #pragma unroll
        for (int qf = 0; qf < 2; ++qf)
            #pragma unroll
            for (int fm = 0; fm < 4; ++fm)
                #pragma unroll
                for (int r = 0; r < 4; ++r) accS[qf][fm][r] = 0.f;
        #pragma unroll
        for (int fm = 0; fm < 4; ++fm) {
            const int key = fm * 16 + c;
            f16x8 kh0 = *(const f16x8*)(KTc + swz(key, g * 8));
            f16x8 kh1 = *(const f16x8*)(KTc + swz(key, 32 + g * 8));
            #pragma unroll
            for (int qf = 0; qf < 2; ++qf) {
                accS[qf][fm] = __builtin_amdgcn_mfma_f32_16x16x32_f16(kh0, qbh[qf][0], accS[qf][fm], 0, 0, 0);
                accS[qf][fm] = __builtin_amdgcn_mfma_f32_16x16x32_f16(kh1, qbh[qf][1], accS[qf][fm], 0, 0, 0);
            }
        }

        // ---- softmax (defer-max THR=8, log2 units) + pack P^T B-frags ----
        f16x4 pb[2][4];   // pb[qf][fm] = B[k=g*4+j][col=c] for 16x16x16 PV
        #pragma unroll
        for (int qf = 0; qf < 2; ++qf) {
            float m0 = fmaxf(fmaxf(accS[qf][0][0], accS[qf][0][1]),
                             fmaxf(accS[qf][0][2], accS[qf][0][3]));
            float m1 = fmaxf(fmaxf(accS[qf][1][0], accS[qf][1][1]),
                             fmaxf(accS[qf][1][2], accS[qf][1][3]));
            float m2 = fmaxf(fmaxf(accS[qf][2][0], accS[qf][2][1]),
                             fmaxf(accS[qf][2][2], accS[qf][2][3]));
            float m3 = fmaxf(fmaxf(accS[qf][3][0], accS[qf][3][1]),
                             fmaxf(accS[qf][3][2], accS[qf][3][3]));
            float tmax = fmaxf(fmaxf(m0, m1), fmaxf(m2, m3));
            tmax = fmaxf(tmax, __shfl_xor(tmax, 16));
            tmax = fmaxf(tmax, __shfl_xor(tmax, 32));
            if (!__all(tmax <= m_run[qf] + 8.f)) {
                const float mnew = fmaxf(m_run[qf], tmax);
                const float corr = exp2f(m_run[qf] - mnew);
                lpart[qf] *= corr;
                #pragma unroll
                for (int nf = 0; nf < 4; ++nf)
                    #pragma unroll
                    for (int r = 0; r < 4; ++r) of[qf][nf][r] *= corr;  // lane-local
                m_run[qf] = mnew;
            }
            float s01 = 0.f, s23 = 0.f;
            #pragma unroll
            for (int fm = 0; fm < 4; ++fm) {
                #pragma unroll
                for (int r = 0; r < 4; ++r) {
                    float pp = exp2f(accS[qf][fm][r] - m_run[qf]);  // <= 2^8
                    accS[qf][fm][r] = pp;
                    if (fm < 2) s01 += pp; else s23 += pp;
                }
                union { f16x4 v4; fp16x2 h2[2]; } u;
                u.h2[0] = __builtin_amdgcn_cvt_pkrtz(accS[qf][fm][0], accS[qf][fm][1]);
                u.h2[1] = __builtin_amdgcn_cvt_pkrtz(accS[qf][fm][2], accS[qf][fm][3]);
                pb[qf][fm] = u.v4;
            }
            lpart[qf] += s01 + s23;   // per-lane; reduce at epilogue
        }

        // ---- PV (16x16x16): V A-frag read ONCE, feeds both qf ----
        #pragma unroll
        for (int nf = 0; nf < 4; ++nf) {
            #pragma unroll
            for (int fm = 0; fm < 4; ++fm) {
                // A-frag: lane (g,c) holds V^T[nf*16 + c][fm*16 + g*4 + j]
                f16x4 va = *(const f16x4*)(VTc + swz(nf * 16 + c, fm * 16 + g * 4));
                of[0][nf] = __builtin_amdgcn_mfma_f32_16x16x16f16(va, pb[0][fm], of[0][nf], 0, 0, 0);
                of[1][nf] = __builtin_amdgcn_mfma_f32_16x16x16f16(va, pb[1][fm], of[1][nf], 0, 0, 0);
            }
        }

        // Barrier: compiler drains vmcnt (DMA done) + lgkmcnt before it.
        __syncthreads();
        cur ^= 1;
    }

    if (S == 1) {
        #pragma unroll
        for (int qf = 0; qf < 2; ++qf) {
            float lr = lpart[qf];
            lr += __shfl_xor(lr, 16);
            lr += __shfl_xor(lr, 32);
            const float linv = 1.0f / lr;   // lane-local (q = c)
            const int n = n0 + wvi * 32 + qf * 16 + c;
            #pragma unroll
            for (int nf = 0; nf < 4; ++nf) {
                float4 o4 = make_float4(of[qf][nf][0] * linv, of[qf][nf][1] * linv,
                                        of[qf][nf][2] * linv, of[qf][nf][3] * linv);
                *(float4*)(out + (((size_t)b * Nn + n) << 6) + nf * 16 + g * 4) = o4;
            }
        }
    } else {
        // Normalized f16 partials (O/l) + (m,l) per row for combine.
        #pragma unroll
        for (int qf = 0; qf < 2; ++qf) {
            float lr = lpart[qf];
            lr += __shfl_xor(lr, 16);
            lr += __shfl_xor(lr, 32);
            const float linv = 1.0f / lr;
            const int n = n0 + wvi * 32 + qf * 16 + c;
            size_t robase = (((size_t)sp * Bn + b) * Nn + n) << 6;
            #pragma unroll
            for (int nf = 0; nf < 4; ++nf) {
                union { f16x4 v4; fp16x2 h2[2]; } u;
                u.h2[0] = __builtin_amdgcn_cvt_pkrtz(of[qf][nf][0] * linv, of[qf][nf][1] * linv);
                u.h2[1] = __builtin_amdgcn_cvt_pkrtz(of[qf][nf][2] * linv, of[qf][nf][3] * linv);
                *(f16x4*)(Opart + robase + nf * 16 + g * 4) = u.v4;
            }
            if (g == 0) {
                ml[((size_t)sp * Bn + b) * Nn + n] = make_float2(m_run[qf], lr);
            }
        }
    }
}

// ---------------------------------------------------------------------------
// Kernel 4: combine normalized split partials. 8 outputs per thread.
// weight_s = exp2(m_s - M) * l_s; out = sum w_s O_s / sum w_s.
__global__ __launch_bounds__(256) void combine(
    const f16* __restrict__ Opart, const float2* __restrict__ ml,
    float* __restrict__ out, int S)
{
    const int idx8 = blockIdx.x * 256 + threadIdx.x;  // b*(N*8) + n*8 + w8
    const int w8 = idx8 & 7;
    const int n  = (idx8 >> 3) & (Nn - 1);
    const int b  = idx8 >> 15;
    float M = -1e30f;
    for (int s = 0; s < S; ++s)
        M = fmaxf(M, ml[((size_t)s * Bn + b) * Nn + n].x);
    float num[8];
    #pragma unroll
    for (int j = 0; j < 8; ++j) num[j] = 0.f;
    float den = 0.f;
    for (int s = 0; s < S; ++s) {
        float2 m2 = ml[((size_t)s * Bn + b) * Nn + n];
        float a = exp2f(m2.x - M) * m2.y;
        f16x8 o8 = *(const f16x8*)(Opart + ((((size_t)s * Bn + b) * Nn + n) << 6) + w8 * 8);
        #pragma unroll
        for (int j = 0; j < 8; ++j) num[j] += a * (float)o8[j];
        den += a;
    }
    const float di = 1.0f / den;
    float* op = out + (((size_t)b * Nn + n) << 6) + w8 * 8;
    float4 lo = make_float4(num[0] * di, num[1] * di, num[2] * di, num[3] * di);
    float4 hi = make_float4(num[4] * di, num[5] * di, num[6] * di, num[7] * di);
    *(float4*)op = lo;
    *(float4*)(op + 4) = hi;
}

// ---------------------------------------------------------------------------
extern "C" void kernel_launch(void* const* d_in, const int* in_sizes, int n_in,
                              void* d_out, int out_size, void* d_ws, size_t ws_size,
                              hipStream_t stream)
{
    const float* v1 = (const float*)d_in[0];
    const float* v2 = (const float*)d_in[1];
    const float* wq = (const float*)d_in[2];
    const float* bq = (const float*)d_in[3];
    const float* wk = (const float*)d_in[4];
    const float* bk = (const float*)d_in[5];
    const float* wv = (const float*)d_in[6];
    const float* bv = (const float*)d_in[7];
    float* out = (float*)d_out;

    char* ws = (char*)d_ws;
    const size_t T = (size_t)TS * sizeof(f16);  // 2 MB per f16 tensor
    f16* Qh = (f16*)(ws + 0 * T);
    f16* Kh = (f16*)(ws + 1 * T);
    f16* Vh = (f16*)(ws + 2 * T);
    f16* Vt = (f16*)(ws + 3 * T);
    const size_t base = 4 * T;                       // 8 MB
    const size_t opartBytes = (size_t)TS * 2;        // 2 MB per split (f16)
    const size_t mlBytes    = (size_t)Bn * Nn * 8;   // 128 KB per split

    int S = 1;
    if      (ws_size >= base + 8 * (opartBytes + mlBytes)) S = 8;
    else if (ws_size >= base + 4 * (opartBytes + mlBytes)) S = 4;
    else if (ws_size >= base + 2 * (opartBytes + mlBytes)) S = 2;

    f16*    Opart = (f16*)(ws + base);
    float2* mlp   = (float2*)(ws + base + (size_t)S * opartBytes);

    qkv_conv<<<dim3(64, 4, 6), 256, 0, stream>>>(v1, v2, wq, bq, wk, bk, wv, bv,
                                                 Qh, Kh, Vh);
    vtrans<<<dim3(64, 4), 256, 0, stream>>>(Vh, Vt);
    attn<<<dim3(16, S, 4), 512, 0, stream>>>(Qh, Kh, Vt, out, Opart, mlp);
    if (S > 1) {
        combine<<<(Bn * Nn * Dd / 8) / 256, 256, 0, stream>>>(Opart, mlp, out, S);
    }
}